// Round 9
// baseline (492.931 us; speedup 1.0000x reference)
//
#include <hip/hip_runtime.h>
#include <math.h>

#define N_USERS 100000
#define NTOT    300000
#define NEDGE   1200000
#define DIM     64

// bucket sort params
#define NPBS    256                             // buckets per side (enc/dec)
#define BROWS2  1172                            // ceil(NTOT/NPBS)
#define CAPS    5376                            // records/bucket cap
#define SCHUNK  4096
#define NCH     ((NEDGE + SCHUNK - 1) / SCHUNK) // 293
#define PAD5    1280                            // 5*256 >= BROWS2

typedef unsigned short ushort_t;
typedef unsigned int uint_t;
typedef __attribute__((ext_vector_type(8))) short short8;
typedef __attribute__((ext_vector_type(8))) unsigned short ushort8;
typedef __attribute__((ext_vector_type(4))) float f32x4;

__device__ __forceinline__ float bf2f(ushort_t u) {
    return __uint_as_float(((uint_t)u) << 16);
}
__device__ __forceinline__ ushort_t f2bf(float x) {
    uint_t b = __float_as_uint(x);
    b += 0x7FFFu + ((b >> 16) & 1u);            // round-to-nearest-even
    return (ushort_t)(b >> 16);
}

// Workspace (~209 MB):
//   emb0b (bf16 ND) | emb1b (bf16 ND)   <- Q (f32 ND) aliases both after they die
//   emb2b (bf16 ND) | KV (bf16 2*ND)    <- staging stE/stD aliases KV front
//   Bt (3*4096 bf16) | rsE | rsD | penc | pdec | gcurE/gcurD/bbE/bbD

// ---------------- emb0 -> bf16 table ----------------------------------------
__global__ __launch_bounds__(256) void convert_emb0(
    const float* __restrict__ uE, const float* __restrict__ iE,
    ushort_t* __restrict__ emb0b) {
    int i = blockIdx.x * 256 + threadIdx.x;
    if (i >= NTOT * 16) return;
    float4 x = (i < N_USERS * 16) ? reinterpret_cast<const float4*>(uE)[i]
                                  : reinterpret_cast<const float4*>(iE)[i - N_USERS * 16];
    ushort4 o;
    o.x = f2bf(x.x); o.y = f2bf(x.y); o.z = f2bf(x.z); o.w = f2bf(x.w);
    reinterpret_cast<ushort4*>(emb0b)[i] = o;
}

// ---------------- qT/kT/vT -> transposed bf16 Bt[c][k] ----------------------
__global__ void bt_prep(const float* __restrict__ qT, const float* __restrict__ kT,
                        const float* __restrict__ vT, ushort_t* __restrict__ Bt) {
    int t = threadIdx.x;
    for (int idx = t; idx < 4096; idx += 256) {
        int k = idx >> 6, c = idx & 63;
        Bt[c * 64 + k]        = f2bf(qT[idx]);
        Bt[4096 + c * 64 + k] = f2bf(kT[idx]);
        Bt[8192 + c * 64 + k] = f2bf(vT[idx]);
    }
}

// ---------------- bucket cursors init ----------------------------------------
__global__ void init_gcur(int* __restrict__ gE, int* __restrict__ gD) {
    int t = threadIdx.x;
    gE[t] = t * CAPS;
    gD[t] = t * CAPS;
}

// ---------------- Phase A: bucket staging (packed records) -------------------
__global__ __launch_bounds__(256) void bucket_stage(
    const int* __restrict__ enc_rows, const int* __restrict__ enc_cols,
    const float* __restrict__ enc_vals, const int* __restrict__ dec_rows,
    const int* __restrict__ dec_cols, int* __restrict__ gcurE,
    int* __restrict__ gcurD, int2* __restrict__ stE, int* __restrict__ stD) {
    __shared__ int cnt[NPBS];
    __shared__ int base[NPBS];
    __shared__ int run[NPBS];
    int t = threadIdx.x;
    bool enc = blockIdx.x < NCH;
    int cb = (enc ? blockIdx.x : blockIdx.x - NCH) * SCHUNK;
    int ce = min(cb + SCHUNK, NEDGE);
    const int* rows = enc ? enc_rows : dec_rows;
    cnt[t] = 0; run[t] = 0;
    __syncthreads();
    for (int i = cb + t; i < ce; i += 256) atomicAdd(&cnt[rows[i] / BROWS2], 1);
    __syncthreads();
    base[t] = atomicAdd(enc ? &gcurE[t] : &gcurD[t], cnt[t]);
    __syncthreads();
    if (enc) {
        for (int i = cb + t; i < ce; i += 256) {
            int r = rows[i];
            int p = r / BROWS2;
            int off = atomicAdd(&run[p], 1);
            int2 v;
            v.x = ((r - p * BROWS2) << 19) | enc_cols[i];
            v.y = __float_as_int(enc_vals[i]);
            stE[base[p] + off] = v;
        }
    } else {
        for (int i = cb + t; i < ce; i += 256) {
            int r = rows[i];
            int p = r / BROWS2;
            int off = atomicAdd(&run[p], 1);
            stD[base[p] + off] = ((r - p * BROWS2) << 19) | dec_cols[i];
        }
    }
}

// ---------------- bucket-count scan (one block) ------------------------------
__global__ __launch_bounds__(256) void scanB(
    const int* __restrict__ gcurE, const int* __restrict__ gcurD,
    int* __restrict__ bbE, int* __restrict__ bbD,
    int* __restrict__ rsE, int* __restrict__ rsD) {
    __shared__ int sh[256];
    int t = threadIdx.x;
    int c = gcurE[t] - t * CAPS;
    sh[t] = c; __syncthreads();
    for (int off = 1; off < 256; off <<= 1) {
        int x = (t >= off) ? sh[t - off] : 0; __syncthreads();
        sh[t] += x; __syncthreads();
    }
    bbE[t] = sh[t] - c;
    __syncthreads();
    int cd = gcurD[t] - t * CAPS;
    sh[t] = cd; __syncthreads();
    for (int off = 1; off < 256; off <<= 1) {
        int x = (t >= off) ? sh[t - off] : 0; __syncthreads();
        sh[t] += x; __syncthreads();
    }
    bbD[t] = sh[t] - cd;
    if (t == 0) { rsE[NTOT] = NEDGE; rsD[NTOT] = NEDGE; }
}

// ---------------- per-bucket LDS counting sort -------------------------------
__global__ __launch_bounds__(256) void sort_b(
    const int* __restrict__ gcurE, const int* __restrict__ gcurD,
    const int* __restrict__ bbE, const int* __restrict__ bbD,
    const int2* __restrict__ stE, const int* __restrict__ stD,
    int2* __restrict__ penc, int* __restrict__ pdec,
    int* __restrict__ rsE, int* __restrict__ rsD) {
    __shared__ int cnt[PAD5];
    __shared__ int rowst[PAD5];
    __shared__ int tsum[256];
    __shared__ int2 outb[CAPS];
    int t = threadIdx.x;
    bool enc = blockIdx.x < NPBS;
    int b = enc ? blockIdx.x : blockIdx.x - NPBS;
    int rowbase = b * BROWS2;
    int s = b * CAPS;
    int e = enc ? gcurE[b] : gcurD[b];
    int gbase = enc ? bbE[b] : bbD[b];
    int n = e - s;

    for (int i = t; i < PAD5; i += 256) cnt[i] = 0;
    __syncthreads();
    if (enc) {
        for (int i = s + t; i < e; i += 256)
            atomicAdd(&cnt[((uint_t)stE[i].x) >> 19], 1);
    } else {
        for (int i = s + t; i < e; i += 256)
            atomicAdd(&cnt[((uint_t)stD[i]) >> 19], 1);
    }
    __syncthreads();
    int b5 = t * 5, sum = 0;
#pragma unroll
    for (int k = 0; k < 5; ++k) { int c = cnt[b5 + k]; rowst[b5 + k] = sum; sum += c; }
    tsum[t] = sum; __syncthreads();
    for (int off = 1; off < 256; off <<= 1) {
        int x = (t >= off) ? tsum[t - off] : 0; __syncthreads();
        tsum[t] += x; __syncthreads();
    }
    int excl = tsum[t] - sum;
#pragma unroll
    for (int k = 0; k < 5; ++k) {
        rowst[b5 + k] += excl;
        cnt[b5 + k] = rowst[b5 + k];            // cnt becomes the scatter cursor
    }
    __syncthreads();

    if (enc) {
        for (int i = s + t; i < e; i += 256) {
            int2 v = stE[i];
            int lr = ((uint_t)v.x) >> 19;
            int pos = atomicAdd(&cnt[lr], 1);
            outb[pos] = make_int2(v.x & 0x7FFFF, v.y);
        }
        __syncthreads();
        for (int i = t; i < n; i += 256) penc[gbase + i] = outb[i];
        int nrows = min(BROWS2, NTOT - rowbase);
        for (int j = t; j < nrows; j += 256) rsE[rowbase + j] = gbase + rowst[j];
    } else {
        int* ob = (int*)outb;
        for (int i = s + t; i < e; i += 256) {
            int v = stD[i];
            int pos = atomicAdd(&cnt[((uint_t)v) >> 19], 1);
            ob[pos] = v & 0x7FFFF;
        }
        __syncthreads();
        for (int i = t; i < n; i += 256) pdec[gbase + i] = ob[i];
        int nrows = min(BROWS2, NTOT - rowbase);
        for (int j = t; j < nrows; j += 256) rsD[rowbase + j] = gbase + rowst[j];
    }
}

// ---------------- GCN layer 1: one WAVE per row, 8 edges in flight -----------
// lane = slot(8) x sub(8): slot = edge slot, sub = 16B dim chunk.
__global__ __launch_bounds__(256) void gcn_gather1(
    const int* __restrict__ rsE, const int2* __restrict__ penc,
    const ushort_t* __restrict__ emb0b, ushort_t* __restrict__ emb1b) {
    int tid = blockIdx.x * 256 + threadIdx.x;
    int row = tid >> 6;
    if (row >= NTOT) return;
    int lane = threadIdx.x & 63;
    int slot = lane >> 3, sub = lane & 7;
    int s = rsE[row], e = rsE[row + 1];
    float acc[8] = {};
    for (int j = s + slot; j < e; j += 8) {
        int2 cv = penc[j];
        float v = __int_as_float(cv.y);
        ushort8 xb = *reinterpret_cast<const ushort8*>(emb0b + (size_t)cv.x * DIM + sub * 8);
#pragma unroll
        for (int k = 0; k < 8; ++k) acc[k] += v * bf2f(xb[k]);
    }
#pragma unroll
    for (int m = 8; m <= 32; m <<= 1)
#pragma unroll
        for (int k = 0; k < 8; ++k) acc[k] += __shfl_xor(acc[k], m);
    if (slot == 0) {
        ushort8 o;
#pragma unroll
        for (int k = 0; k < 8; ++k) o[k] = f2bf(acc[k]);
        *reinterpret_cast<ushort8*>(emb1b + (size_t)row * DIM + sub * 8) = o;
    }
}

// ---------------- GCN layer 2 + layer-sum fusion (wave per row) --------------
__global__ __launch_bounds__(256) void gcn_gather2(
    const int* __restrict__ rsE, const int2* __restrict__ penc,
    const ushort_t* __restrict__ emb1b, const float* __restrict__ uE,
    const float* __restrict__ iE, ushort_t* __restrict__ emb2b,
    float* __restrict__ out) {
    int tid = blockIdx.x * 256 + threadIdx.x;
    int row = tid >> 6;
    if (row >= NTOT) return;
    int lane = threadIdx.x & 63;
    int slot = lane >> 3, sub = lane & 7;
    int s = rsE[row], e = rsE[row + 1];
    float acc[8] = {};
    for (int j = s + slot; j < e; j += 8) {
        int2 cv = penc[j];
        float v = __int_as_float(cv.y);
        ushort8 xb = *reinterpret_cast<const ushort8*>(emb1b + (size_t)cv.x * DIM + sub * 8);
#pragma unroll
        for (int k = 0; k < 8; ++k) acc[k] += v * bf2f(xb[k]);
    }
#pragma unroll
    for (int m = 8; m <= 32; m <<= 1)
#pragma unroll
        for (int k = 0; k < 8; ++k) acc[k] += __shfl_xor(acc[k], m);
    if (slot == 0) {
        ushort8 o2;
#pragma unroll
        for (int k = 0; k < 8; ++k) o2[k] = f2bf(acc[k]);
        *reinterpret_cast<ushort8*>(emb2b + (size_t)row * DIM + sub * 8) = o2;
        const float* e0p = (row < N_USERS) ? uE + (size_t)row * DIM
                                           : iE + (size_t)(row - N_USERS) * DIM;
        float4 e0a = reinterpret_cast<const float4*>(e0p)[sub * 2];
        float4 e0b = reinterpret_cast<const float4*>(e0p)[sub * 2 + 1];
        ushort8 e1 = *reinterpret_cast<const ushort8*>(emb1b + (size_t)row * DIM + sub * 8);
        float4 oa, ob;
        oa.x = e0a.x + bf2f(e1[0]) + acc[0]; oa.y = e0a.y + bf2f(e1[1]) + acc[1];
        oa.z = e0a.z + bf2f(e1[2]) + acc[2]; oa.w = e0a.w + bf2f(e1[3]) + acc[3];
        ob.x = e0b.x + bf2f(e1[4]) + acc[4]; ob.y = e0b.y + bf2f(e1[5]) + acc[5];
        ob.z = e0b.z + bf2f(e1[6]) + acc[6]; ob.w = e0b.w + bf2f(e1[7]) + acc[7];
        reinterpret_cast<float4*>(out + (size_t)row * DIM)[sub * 2] = oa;
        reinterpret_cast<float4*>(out + (size_t)row * DIM)[sub * 2 + 1] = ob;
    }
}

// ---------------- MFMA Q/K/V: [NTOT x 64] bf16 @ 3x [64 x 64] bf16 -----------
__global__ __launch_bounds__(256) void qkv_mfma(
    const ushort_t* __restrict__ emb2b, const ushort_t* __restrict__ Bt,
    float* __restrict__ Q, ushort_t* __restrict__ KV) {
    int tid = threadIdx.x;
    int w = tid >> 6, lane = tid & 63;
    int lr = lane & 15, lh = lane >> 4;
    int R0 = blockIdx.x * 256 + w * 64;

    short8 a[4][2];
    short8 z8 = {0, 0, 0, 0, 0, 0, 0, 0};
#pragma unroll
    for (int m = 0; m < 4; ++m) {
        int row = R0 + m * 16 + lr;
        if (row < NTOT) {
            const ushort_t* ap = emb2b + (size_t)row * 64 + lh * 8;
            a[m][0] = *reinterpret_cast<const short8*>(ap);
            a[m][1] = *reinterpret_cast<const short8*>(ap + 32);
        } else {
            a[m][0] = z8; a[m][1] = z8;
        }
    }

#pragma unroll
    for (int n = 0; n < 4; ++n) {
        int col = n * 16 + lr;
        const ushort_t* bp = Bt + (size_t)col * 64 + lh * 8;
        short8 bq0 = *reinterpret_cast<const short8*>(bp);
        short8 bq1 = *reinterpret_cast<const short8*>(bp + 32);
        short8 bk0 = *reinterpret_cast<const short8*>(bp + 4096);
        short8 bk1 = *reinterpret_cast<const short8*>(bp + 4096 + 32);
        short8 bv0 = *reinterpret_cast<const short8*>(bp + 8192);
        short8 bv1 = *reinterpret_cast<const short8*>(bp + 8192 + 32);
#pragma unroll
        for (int m = 0; m < 4; ++m) {
            f32x4 aq = {0.f, 0.f, 0.f, 0.f};
            f32x4 ak = {0.f, 0.f, 0.f, 0.f};
            f32x4 av = {0.f, 0.f, 0.f, 0.f};
            aq = __builtin_amdgcn_mfma_f32_16x16x32_bf16(a[m][0], bq0, aq, 0, 0, 0);
            aq = __builtin_amdgcn_mfma_f32_16x16x32_bf16(a[m][1], bq1, aq, 0, 0, 0);
            ak = __builtin_amdgcn_mfma_f32_16x16x32_bf16(a[m][0], bk0, ak, 0, 0, 0);
            ak = __builtin_amdgcn_mfma_f32_16x16x32_bf16(a[m][1], bk1, ak, 0, 0, 0);
            av = __builtin_amdgcn_mfma_f32_16x16x32_bf16(a[m][0], bv0, av, 0, 0, 0);
            av = __builtin_amdgcn_mfma_f32_16x16x32_bf16(a[m][1], bv1, av, 0, 0, 0);
            int rbase = R0 + m * 16 + lh * 4;
#pragma unroll
            for (int r = 0; r < 4; ++r) {
                int srow = rbase + r;
                if (srow < NTOT) {
                    Q[(size_t)srow * 64 + col] = aq[r];
                    KV[(size_t)srow * 128 + col] = f2bf(ak[r]);
                    KV[(size_t)srow * 128 + 64 + col] = f2bf(av[r]);
                }
            }
        }
    }
}

// ---------------- fused GT: one WAVE per row, 8 edges in flight ---------------
// lane = slot(8) x sub(8); head = sub>>1 (dh=16 spans 2 lanes, shfl_xor(1)).
__global__ __launch_bounds__(256) void gt_fused(
    const int* __restrict__ rsD, const int* __restrict__ pdec,
    const float* __restrict__ Q, const ushort_t* __restrict__ KV,
    float* __restrict__ out) {
    int tid = blockIdx.x * 256 + threadIdx.x;
    int row = tid >> 6;
    if (row >= NTOT) return;
    int lane = threadIdx.x & 63;
    int slot = lane >> 3, sub = lane & 7;
    int s = rsD[row], e = rsD[row + 1];
    float qv[8];
    {
        float4 qa = reinterpret_cast<const float4*>(Q + (size_t)row * DIM)[sub * 2];
        float4 qb = reinterpret_cast<const float4*>(Q + (size_t)row * DIM)[sub * 2 + 1];
        qv[0] = qa.x; qv[1] = qa.y; qv[2] = qa.z; qv[3] = qa.w;
        qv[4] = qb.x; qv[5] = qb.y; qv[6] = qb.z; qv[7] = qb.w;
    }
    float norm = 0.f;
    float acc[8] = {};
    for (int j = s + slot; j < e; j += 8) {
        int c = pdec[j];
        const ushort_t* kvrow = KV + (size_t)c * 128;
        ushort8 kb = *reinterpret_cast<const ushort8*>(kvrow + sub * 8);
        ushort8 vb = *reinterpret_cast<const ushort8*>(kvrow + 64 + sub * 8);
        float p = 0.f;
#pragma unroll
        for (int k = 0; k < 8; ++k) p += qv[k] * bf2f(kb[k]);
        p += __shfl_xor(p, 1);                  // pair-sum -> per-head dot
        p = fminf(10.f, fmaxf(-10.f, p));
        float ex = __expf(p);
        norm += ex;
#pragma unroll
        for (int k = 0; k < 8; ++k) acc[k] += ex * bf2f(vb[k]);
    }
#pragma unroll
    for (int m = 8; m <= 32; m <<= 1) {
        norm += __shfl_xor(norm, m);
#pragma unroll
        for (int k = 0; k < 8; ++k) acc[k] += __shfl_xor(acc[k], m);
    }
    if (slot == 0) {
        float inv = 1.f / (norm + 1e-8f);
        float4 oa = reinterpret_cast<float4*>(out + (size_t)row * DIM)[sub * 2];
        float4 ob = reinterpret_cast<float4*>(out + (size_t)row * DIM)[sub * 2 + 1];
        oa.x += acc[0] * inv; oa.y += acc[1] * inv;
        oa.z += acc[2] * inv; oa.w += acc[3] * inv;
        ob.x += acc[4] * inv; ob.y += acc[5] * inv;
        ob.z += acc[6] * inv; ob.w += acc[7] * inv;
        reinterpret_cast<float4*>(out + (size_t)row * DIM)[sub * 2] = oa;
        reinterpret_cast<float4*>(out + (size_t)row * DIM)[sub * 2 + 1] = ob;
    }
}

extern "C" void kernel_launch(void* const* d_in, const int* in_sizes, int n_in,
                              void* d_out, int out_size, void* d_ws, size_t ws_size,
                              hipStream_t stream) {
    const float* uE       = (const float*)d_in[0];
    const float* iE       = (const float*)d_in[1];
    const float* qT       = (const float*)d_in[2];
    const float* kT       = (const float*)d_in[3];
    const float* vT       = (const float*)d_in[4];
    const float* enc_vals = (const float*)d_in[5];
    const int*   enc_rows = (const int*)d_in[6];
    const int*   enc_cols = (const int*)d_in[7];
    const int*   dec_rows = (const int*)d_in[8];
    const int*   dec_cols = (const int*)d_in[9];
    float* out = (float*)d_out;

    const size_t ND = (size_t)NTOT * DIM;       // 19.2M
    ushort_t* emb0b = (ushort_t*)d_ws;                      // bf16, ND
    ushort_t* emb1b = emb0b + ND;                           // bf16, ND
    ushort_t* emb2b = emb1b + ND;                           // bf16, ND
    ushort_t* KV    = emb2b + ND;                           // bf16, 2*ND
    ushort_t* Bt    = KV + 2 * ND;                          // bf16, 3*4096
    int*      rsE   = (int*)(Bt + 3 * 4096);                // NTOT+1
    int*      rsD   = rsE + NTOT + 1;                       // NTOT+1
    int2*     penc  = (int2*)(rsD + NTOT + 1);              // NEDGE int2
    int*      pdec  = (int*)(penc + NEDGE);                 // NEDGE int
    int*      gcurE = pdec + NEDGE;                         // 256
    int*      gcurD = gcurE + NPBS;                         // 256
    int*      bbE   = gcurD + NPBS;                         // 256
    int*      bbD   = bbE + NPBS;                           // 256

    float*    Q     = (float*)emb0b;            // aliases emb0b+emb1b (dead by qkv)
    int2*     stE   = (int2*)KV;                // staging aliases KV (dead until qkv)
    int*      stD   = (int*)(stE + (size_t)NPBS * CAPS);

    const int GB  = (NTOT * 16) / 256;          // 18750 (256B/row kernels)
    const int WB  = (NTOT * 64 + 255) / 256;    // 75000 (wave-per-row kernels)
    const int QB  = (NTOT + 255) / 256;         // 1172

    init_gcur<<<1, 256, 0, stream>>>(gcurE, gcurD);
    convert_emb0<<<GB, 256, 0, stream>>>(uE, iE, emb0b);
    bt_prep<<<1, 256, 0, stream>>>(qT, kT, vT, Bt);

    bucket_stage<<<2 * NCH, 256, 0, stream>>>(enc_rows, enc_cols, enc_vals,
                                              dec_rows, dec_cols, gcurE, gcurD, stE, stD);
    scanB<<<1, 256, 0, stream>>>(gcurE, gcurD, bbE, bbD, rsE, rsD);
    sort_b<<<2 * NPBS, 256, 0, stream>>>(gcurE, gcurD, bbE, bbD, stE, stD,
                                         penc, pdec, rsE, rsD);

    gcn_gather1<<<WB, 256, 0, stream>>>(rsE, penc, emb0b, emb1b);
    gcn_gather2<<<WB, 256, 0, stream>>>(rsE, penc, emb1b, uE, iE, emb2b, out);

    qkv_mfma<<<QB, 256, 0, stream>>>(emb2b, Bt, Q, KV);
    gt_fused<<<WB, 256, 0, stream>>>(rsD, pdec, Q, KV, out);
}

// Round 10
// 408.194 us; speedup vs baseline: 1.2076x; 1.2076x over previous
//
#include <hip/hip_runtime.h>
#include <math.h>

#define N_USERS 100000
#define NTOT    300000
#define NEDGE   1200000
#define DIM     64

// bucket sort params
#define NPBS    256                             // buckets per side (enc/dec)
#define BROWS2  1172                            // ceil(NTOT/NPBS)
#define CAPS    5376                            // records/bucket cap
#define SCHUNK  4096
#define NCH     ((NEDGE + SCHUNK - 1) / SCHUNK) // 293
#define PAD5    1280                            // 5*256 >= BROWS2

typedef unsigned short ushort_t;
typedef unsigned int uint_t;
typedef __attribute__((ext_vector_type(8))) short short8;
typedef __attribute__((ext_vector_type(8))) unsigned short ushort8;
typedef __attribute__((ext_vector_type(4))) float f32x4;

__device__ __forceinline__ float bf2f(ushort_t u) {
    return __uint_as_float(((uint_t)u) << 16);
}
__device__ __forceinline__ ushort_t f2bf(float x) {
    uint_t b = __float_as_uint(x);
    b += 0x7FFFu + ((b >> 16) & 1u);            // round-to-nearest-even
    return (ushort_t)(b >> 16);
}

// Workspace (~209 MB):
//   emb0b (bf16 ND) | emb1b (bf16 ND)   <- Q (f32 ND) aliases both after they die
//   emb2b (bf16 ND) | KV (bf16 2*ND, interleaved k/v chunks) <- staging aliases
//   Bt (3*4096 bf16) | rsE | rsD | penc | pdec | gcurE/gcurD/bbE/bbD

// ---------------- emb0 -> bf16 table ----------------------------------------
__global__ __launch_bounds__(256) void convert_emb0(
    const float* __restrict__ uE, const float* __restrict__ iE,
    ushort_t* __restrict__ emb0b) {
    int i = blockIdx.x * 256 + threadIdx.x;
    if (i >= NTOT * 16) return;
    float4 x = (i < N_USERS * 16) ? reinterpret_cast<const float4*>(uE)[i]
                                  : reinterpret_cast<const float4*>(iE)[i - N_USERS * 16];
    ushort4 o;
    o.x = f2bf(x.x); o.y = f2bf(x.y); o.z = f2bf(x.z); o.w = f2bf(x.w);
    reinterpret_cast<ushort4*>(emb0b)[i] = o;
}

// ---------------- qT/kT/vT -> transposed bf16 Bt[c][k] ----------------------
__global__ void bt_prep(const float* __restrict__ qT, const float* __restrict__ kT,
                        const float* __restrict__ vT, ushort_t* __restrict__ Bt) {
    int t = threadIdx.x;
    for (int idx = t; idx < 4096; idx += 256) {
        int k = idx >> 6, c = idx & 63;
        Bt[c * 64 + k]        = f2bf(qT[idx]);
        Bt[4096 + c * 64 + k] = f2bf(kT[idx]);
        Bt[8192 + c * 64 + k] = f2bf(vT[idx]);
    }
}

// ---------------- bucket cursors init ----------------------------------------
__global__ void init_gcur(int* __restrict__ gE, int* __restrict__ gD) {
    int t = threadIdx.x;
    gE[t] = t * CAPS;
    gD[t] = t * CAPS;
}

// ---------------- Phase A: bucket staging (packed records) -------------------
__global__ __launch_bounds__(256) void bucket_stage(
    const int* __restrict__ enc_rows, const int* __restrict__ enc_cols,
    const float* __restrict__ enc_vals, const int* __restrict__ dec_rows,
    const int* __restrict__ dec_cols, int* __restrict__ gcurE,
    int* __restrict__ gcurD, int2* __restrict__ stE, int* __restrict__ stD) {
    __shared__ int cnt[NPBS];
    __shared__ int base[NPBS];
    __shared__ int run[NPBS];
    int t = threadIdx.x;
    bool enc = blockIdx.x < NCH;
    int cb = (enc ? blockIdx.x : blockIdx.x - NCH) * SCHUNK;
    int ce = min(cb + SCHUNK, NEDGE);
    const int* rows = enc ? enc_rows : dec_rows;
    cnt[t] = 0; run[t] = 0;
    __syncthreads();
    for (int i = cb + t; i < ce; i += 256) atomicAdd(&cnt[rows[i] / BROWS2], 1);
    __syncthreads();
    base[t] = atomicAdd(enc ? &gcurE[t] : &gcurD[t], cnt[t]);
    __syncthreads();
    if (enc) {
        for (int i = cb + t; i < ce; i += 256) {
            int r = rows[i];
            int p = r / BROWS2;
            int off = atomicAdd(&run[p], 1);
            int2 v;
            v.x = ((r - p * BROWS2) << 19) | enc_cols[i];
            v.y = __float_as_int(enc_vals[i]);
            stE[base[p] + off] = v;
        }
    } else {
        for (int i = cb + t; i < ce; i += 256) {
            int r = rows[i];
            int p = r / BROWS2;
            int off = atomicAdd(&run[p], 1);
            stD[base[p] + off] = ((r - p * BROWS2) << 19) | dec_cols[i];
        }
    }
}

// ---------------- bucket-count scan (one block) ------------------------------
__global__ __launch_bounds__(256) void scanB(
    const int* __restrict__ gcurE, const int* __restrict__ gcurD,
    int* __restrict__ bbE, int* __restrict__ bbD,
    int* __restrict__ rsE, int* __restrict__ rsD) {
    __shared__ int sh[256];
    int t = threadIdx.x;
    int c = gcurE[t] - t * CAPS;
    sh[t] = c; __syncthreads();
    for (int off = 1; off < 256; off <<= 1) {
        int x = (t >= off) ? sh[t - off] : 0; __syncthreads();
        sh[t] += x; __syncthreads();
    }
    bbE[t] = sh[t] - c;
    __syncthreads();
    int cd = gcurD[t] - t * CAPS;
    sh[t] = cd; __syncthreads();
    for (int off = 1; off < 256; off <<= 1) {
        int x = (t >= off) ? sh[t - off] : 0; __syncthreads();
        sh[t] += x; __syncthreads();
    }
    bbD[t] = sh[t] - cd;
    if (t == 0) { rsE[NTOT] = NEDGE; rsD[NTOT] = NEDGE; }
}

// ---------------- per-bucket LDS counting sort -------------------------------
__global__ __launch_bounds__(256) void sort_b(
    const int* __restrict__ gcurE, const int* __restrict__ gcurD,
    const int* __restrict__ bbE, const int* __restrict__ bbD,
    const int2* __restrict__ stE, const int* __restrict__ stD,
    int2* __restrict__ penc, int* __restrict__ pdec,
    int* __restrict__ rsE, int* __restrict__ rsD) {
    __shared__ int cnt[PAD5];
    __shared__ int rowst[PAD5];
    __shared__ int tsum[256];
    __shared__ int2 outb[CAPS];
    int t = threadIdx.x;
    bool enc = blockIdx.x < NPBS;
    int b = enc ? blockIdx.x : blockIdx.x - NPBS;
    int rowbase = b * BROWS2;
    int s = b * CAPS;
    int e = enc ? gcurE[b] : gcurD[b];
    int gbase = enc ? bbE[b] : bbD[b];
    int n = e - s;

    for (int i = t; i < PAD5; i += 256) cnt[i] = 0;
    __syncthreads();
    if (enc) {
        for (int i = s + t; i < e; i += 256)
            atomicAdd(&cnt[((uint_t)stE[i].x) >> 19], 1);
    } else {
        for (int i = s + t; i < e; i += 256)
            atomicAdd(&cnt[((uint_t)stD[i]) >> 19], 1);
    }
    __syncthreads();
    int b5 = t * 5, sum = 0;
#pragma unroll
    for (int k = 0; k < 5; ++k) { int c = cnt[b5 + k]; rowst[b5 + k] = sum; sum += c; }
    tsum[t] = sum; __syncthreads();
    for (int off = 1; off < 256; off <<= 1) {
        int x = (t >= off) ? tsum[t - off] : 0; __syncthreads();
        tsum[t] += x; __syncthreads();
    }
    int excl = tsum[t] - sum;
#pragma unroll
    for (int k = 0; k < 5; ++k) {
        rowst[b5 + k] += excl;
        cnt[b5 + k] = rowst[b5 + k];            // cnt becomes the scatter cursor
    }
    __syncthreads();

    if (enc) {
        for (int i = s + t; i < e; i += 256) {
            int2 v = stE[i];
            int lr = ((uint_t)v.x) >> 19;
            int pos = atomicAdd(&cnt[lr], 1);
            outb[pos] = make_int2(v.x & 0x7FFFF, v.y);
        }
        __syncthreads();
        for (int i = t; i < n; i += 256) penc[gbase + i] = outb[i];
        int nrows = min(BROWS2, NTOT - rowbase);
        for (int j = t; j < nrows; j += 256) rsE[rowbase + j] = gbase + rowst[j];
    } else {
        int* ob = (int*)outb;
        for (int i = s + t; i < e; i += 256) {
            int v = stD[i];
            int pos = atomicAdd(&cnt[((uint_t)v) >> 19], 1);
            ob[pos] = v & 0x7FFFF;
        }
        __syncthreads();
        for (int i = t; i < n; i += 256) pdec[gbase + i] = ob[i];
        int nrows = min(BROWS2, NTOT - rowbase);
        for (int j = t; j < nrows; j += 256) rsD[rowbase + j] = gbase + rowst[j];
    }
}

// ---------------- GCN layer 1: 32 lanes/row = 2 edge-slots x 16 dim-lanes ----
__global__ __launch_bounds__(256) void gcn_gather1(
    const int* __restrict__ rsE, const int2* __restrict__ penc,
    const ushort_t* __restrict__ emb0b, ushort_t* __restrict__ emb1b) {
    int tid = blockIdx.x * 256 + threadIdx.x;
    int row = tid >> 5;
    if (row >= NTOT) return;
    int lane = threadIdx.x & 31;
    int slot = lane >> 4, l = lane & 15;
    int s = rsE[row], e = rsE[row + 1];
    float4 acc = {0.f, 0.f, 0.f, 0.f};
    for (int j = s + slot; j < e; j += 2) {
        int2 cv = penc[j];
        float v = __int_as_float(cv.y);
        ushort4 xb = reinterpret_cast<const ushort4*>(emb0b + (size_t)cv.x * DIM)[l];
        acc.x += v * bf2f(xb.x); acc.y += v * bf2f(xb.y);
        acc.z += v * bf2f(xb.z); acc.w += v * bf2f(xb.w);
    }
    acc.x += __shfl_xor(acc.x, 16); acc.y += __shfl_xor(acc.y, 16);
    acc.z += __shfl_xor(acc.z, 16); acc.w += __shfl_xor(acc.w, 16);
    if (slot == 0) {
        ushort4 o;
        o.x = f2bf(acc.x); o.y = f2bf(acc.y); o.z = f2bf(acc.z); o.w = f2bf(acc.w);
        reinterpret_cast<ushort4*>(emb1b)[(size_t)row * 16 + l] = o;
    }
}

// ---------------- GCN layer 2 + layer-sum fusion (2-slot) --------------------
__global__ __launch_bounds__(256) void gcn_gather2(
    const int* __restrict__ rsE, const int2* __restrict__ penc,
    const ushort_t* __restrict__ emb1b, const float* __restrict__ uE,
    const float* __restrict__ iE, ushort_t* __restrict__ emb2b,
    float* __restrict__ out) {
    int tid = blockIdx.x * 256 + threadIdx.x;
    int row = tid >> 5;
    if (row >= NTOT) return;
    int lane = threadIdx.x & 31;
    int slot = lane >> 4, l = lane & 15;
    int s = rsE[row], e = rsE[row + 1];
    float4 acc = {0.f, 0.f, 0.f, 0.f};
    for (int j = s + slot; j < e; j += 2) {
        int2 cv = penc[j];
        float v = __int_as_float(cv.y);
        ushort4 xb = reinterpret_cast<const ushort4*>(emb1b + (size_t)cv.x * DIM)[l];
        acc.x += v * bf2f(xb.x); acc.y += v * bf2f(xb.y);
        acc.z += v * bf2f(xb.z); acc.w += v * bf2f(xb.w);
    }
    acc.x += __shfl_xor(acc.x, 16); acc.y += __shfl_xor(acc.y, 16);
    acc.z += __shfl_xor(acc.z, 16); acc.w += __shfl_xor(acc.w, 16);
    if (slot == 0) {
        ushort4 o2;
        o2.x = f2bf(acc.x); o2.y = f2bf(acc.y); o2.z = f2bf(acc.z); o2.w = f2bf(acc.w);
        reinterpret_cast<ushort4*>(emb2b)[(size_t)row * 16 + l] = o2;
        const float* e0p = (row < N_USERS) ? uE + (size_t)row * DIM
                                           : iE + (size_t)(row - N_USERS) * DIM;
        float4 e0 = reinterpret_cast<const float4*>(e0p)[l];
        ushort4 e1 = reinterpret_cast<const ushort4*>(emb1b)[(size_t)row * 16 + l];
        float4 o;
        o.x = e0.x + bf2f(e1.x) + acc.x; o.y = e0.y + bf2f(e1.y) + acc.y;
        o.z = e0.z + bf2f(e1.z) + acc.z; o.w = e0.w + bf2f(e1.w) + acc.w;
        reinterpret_cast<float4*>(out)[(size_t)row * 16 + l] = o;
    }
}

// ---------------- MFMA Q/K/V; KV written INTERLEAVED per 4-elem chunk --------
// KV row layout: chunk i (i=0..15) = [k(4i..4i+3), v(4i..4i+3)]  (16 bf16)
__global__ __launch_bounds__(256) void qkv_mfma(
    const ushort_t* __restrict__ emb2b, const ushort_t* __restrict__ Bt,
    float* __restrict__ Q, ushort_t* __restrict__ KV) {
    int tid = threadIdx.x;
    int w = tid >> 6, lane = tid & 63;
    int lr = lane & 15, lh = lane >> 4;
    int R0 = blockIdx.x * 256 + w * 64;

    short8 a[4][2];
    short8 z8 = {0, 0, 0, 0, 0, 0, 0, 0};
#pragma unroll
    for (int m = 0; m < 4; ++m) {
        int row = R0 + m * 16 + lr;
        if (row < NTOT) {
            const ushort_t* ap = emb2b + (size_t)row * 64 + lh * 8;
            a[m][0] = *reinterpret_cast<const short8*>(ap);
            a[m][1] = *reinterpret_cast<const short8*>(ap + 32);
        } else {
            a[m][0] = z8; a[m][1] = z8;
        }
    }

#pragma unroll
    for (int n = 0; n < 4; ++n) {
        int col = n * 16 + lr;
        const ushort_t* bp = Bt + (size_t)col * 64 + lh * 8;
        short8 bq0 = *reinterpret_cast<const short8*>(bp);
        short8 bq1 = *reinterpret_cast<const short8*>(bp + 32);
        short8 bk0 = *reinterpret_cast<const short8*>(bp + 4096);
        short8 bk1 = *reinterpret_cast<const short8*>(bp + 4096 + 32);
        short8 bv0 = *reinterpret_cast<const short8*>(bp + 8192);
        short8 bv1 = *reinterpret_cast<const short8*>(bp + 8192 + 32);
        int ip = ((col >> 2) << 3) + (col & 3);    // interleaved position
#pragma unroll
        for (int m = 0; m < 4; ++m) {
            f32x4 aq = {0.f, 0.f, 0.f, 0.f};
            f32x4 ak = {0.f, 0.f, 0.f, 0.f};
            f32x4 av = {0.f, 0.f, 0.f, 0.f};
            aq = __builtin_amdgcn_mfma_f32_16x16x32_bf16(a[m][0], bq0, aq, 0, 0, 0);
            aq = __builtin_amdgcn_mfma_f32_16x16x32_bf16(a[m][1], bq1, aq, 0, 0, 0);
            ak = __builtin_amdgcn_mfma_f32_16x16x32_bf16(a[m][0], bk0, ak, 0, 0, 0);
            ak = __builtin_amdgcn_mfma_f32_16x16x32_bf16(a[m][1], bk1, ak, 0, 0, 0);
            av = __builtin_amdgcn_mfma_f32_16x16x32_bf16(a[m][0], bv0, av, 0, 0, 0);
            av = __builtin_amdgcn_mfma_f32_16x16x32_bf16(a[m][1], bv1, av, 0, 0, 0);
            int rbase = R0 + m * 16 + lh * 4;
#pragma unroll
            for (int r = 0; r < 4; ++r) {
                int srow = rbase + r;
                if (srow < NTOT) {
                    Q[(size_t)srow * 64 + col] = aq[r];
                    KV[(size_t)srow * 128 + ip] = f2bf(ak[r]);
                    KV[(size_t)srow * 128 + ip + 4] = f2bf(av[r]);
                }
            }
        }
    }
}

// ---------------- fused GT: 32 lanes/row, one 16B KV load per edge/lane ------
__global__ __launch_bounds__(256) void gt_fused(
    const int* __restrict__ rsD, const int* __restrict__ pdec,
    const float* __restrict__ Q, const ushort_t* __restrict__ KV,
    float* __restrict__ out) {
    int tid = blockIdx.x * 256 + threadIdx.x;
    int row = tid >> 5;
    if (row >= NTOT) return;
    int lane = threadIdx.x & 31;
    int slot = lane >> 4, l = lane & 15;
    int s = rsD[row], e = rsD[row + 1];
    float4 q = reinterpret_cast<const float4*>(Q)[(size_t)row * 16 + l];
    float norm = 0.f;
    float4 acc = {0.f, 0.f, 0.f, 0.f};
    for (int j = s + slot; j < e; j += 2) {
        int c = pdec[j];
        ushort8 kv = *reinterpret_cast<const ushort8*>(KV + (size_t)c * 128 + l * 8);
        float p = q.x * bf2f(kv[0]) + q.y * bf2f(kv[1])
                + q.z * bf2f(kv[2]) + q.w * bf2f(kv[3]);
        p += __shfl_xor(p, 1);
        p += __shfl_xor(p, 2);
        p = fminf(10.f, fmaxf(-10.f, p));
        float ex = __expf(p);
        norm += ex;
        acc.x += ex * bf2f(kv[4]); acc.y += ex * bf2f(kv[5]);
        acc.z += ex * bf2f(kv[6]); acc.w += ex * bf2f(kv[7]);
    }
    norm  += __shfl_xor(norm, 16);
    acc.x += __shfl_xor(acc.x, 16); acc.y += __shfl_xor(acc.y, 16);
    acc.z += __shfl_xor(acc.z, 16); acc.w += __shfl_xor(acc.w, 16);
    if (slot == 0) {
        float inv = 1.f / (norm + 1e-8f);
        float4 o = reinterpret_cast<float4*>(out)[(size_t)row * 16 + l];
        o.x += acc.x * inv; o.y += acc.y * inv;
        o.z += acc.z * inv; o.w += acc.w * inv;
        reinterpret_cast<float4*>(out)[(size_t)row * 16 + l] = o;
    }
}

extern "C" void kernel_launch(void* const* d_in, const int* in_sizes, int n_in,
                              void* d_out, int out_size, void* d_ws, size_t ws_size,
                              hipStream_t stream) {
    const float* uE       = (const float*)d_in[0];
    const float* iE       = (const float*)d_in[1];
    const float* qT       = (const float*)d_in[2];
    const float* kT       = (const float*)d_in[3];
    const float* vT       = (const float*)d_in[4];
    const float* enc_vals = (const float*)d_in[5];
    const int*   enc_rows = (const int*)d_in[6];
    const int*   enc_cols = (const int*)d_in[7];
    const int*   dec_rows = (const int*)d_in[8];
    const int*   dec_cols = (const int*)d_in[9];
    float* out = (float*)d_out;

    const size_t ND = (size_t)NTOT * DIM;       // 19.2M
    ushort_t* emb0b = (ushort_t*)d_ws;                      // bf16, ND
    ushort_t* emb1b = emb0b + ND;                           // bf16, ND
    ushort_t* emb2b = emb1b + ND;                           // bf16, ND
    ushort_t* KV    = emb2b + ND;                           // bf16, 2*ND (interleaved)
    ushort_t* Bt    = KV + 2 * ND;                          // bf16, 3*4096
    int*      rsE   = (int*)(Bt + 3 * 4096);                // NTOT+1
    int*      rsD   = rsE + NTOT + 1;                       // NTOT+1
    int2*     penc  = (int2*)(rsD + NTOT + 1);              // NEDGE int2
    int*      pdec  = (int*)(penc + NEDGE);                 // NEDGE int
    int*      gcurE = pdec + NEDGE;                         // 256
    int*      gcurD = gcurE + NPBS;                         // 256
    int*      bbE   = gcurD + NPBS;                         // 256
    int*      bbD   = bbE + NPBS;                           // 256

    float*    Q     = (float*)emb0b;            // aliases emb0b+emb1b (dead by qkv)
    int2*     stE   = (int2*)KV;                // staging aliases KV (dead until qkv)
    int*      stD   = (int*)(stE + (size_t)NPBS * CAPS);

    const int GB  = (NTOT * 16) / 256;          // 18750 (256B/row kernels)
    const int WB2 = (NTOT * 32 + 255) / 256;    // 37500 (2-slot kernels)
    const int QB  = (NTOT + 255) / 256;         // 1172

    init_gcur<<<1, 256, 0, stream>>>(gcurE, gcurD);
    convert_emb0<<<GB, 256, 0, stream>>>(uE, iE, emb0b);
    bt_prep<<<1, 256, 0, stream>>>(qT, kT, vT, Bt);

    bucket_stage<<<2 * NCH, 256, 0, stream>>>(enc_rows, enc_cols, enc_vals,
                                              dec_rows, dec_cols, gcurE, gcurD, stE, stD);
    scanB<<<1, 256, 0, stream>>>(gcurE, gcurD, bbE, bbD, rsE, rsD);
    sort_b<<<2 * NPBS, 256, 0, stream>>>(gcurE, gcurD, bbE, bbD, stE, stD,
                                         penc, pdec, rsE, rsD);

    gcn_gather1<<<WB2, 256, 0, stream>>>(rsE, penc, emb0b, emb1b);
    gcn_gather2<<<WB2, 256, 0, stream>>>(rsE, penc, emb1b, uE, iE, emb2b, out);

    qkv_mfma<<<QB, 256, 0, stream>>>(emb2b, Bt, Q, KV);
    gt_fused<<<WB2, 256, 0, stream>>>(rsD, pdec, Q, KV, out);
}

// Round 11
// 374.860 us; speedup vs baseline: 1.3150x; 1.0889x over previous
//
#include <hip/hip_runtime.h>
#include <math.h>

#define N_USERS 100000
#define NTOT    300000
#define NEDGE   1200000
#define DIM     64

// bucket sort params
#define NPBS    256                             // buckets per side (enc/dec)
#define BROWS2  1172                            // ceil(NTOT/NPBS)
#define CAPS    5376                            // records/bucket cap
#define SCHUNK  4096
#define NCH     ((NEDGE + SCHUNK - 1) / SCHUNK) // 293
#define PAD5    1280                            // 5*256 >= BROWS2

typedef unsigned short ushort_t;
typedef unsigned int uint_t;
typedef __attribute__((ext_vector_type(8))) short short8;
typedef __attribute__((ext_vector_type(8))) unsigned short ushort8;
typedef __attribute__((ext_vector_type(4))) float f32x4;

__device__ __forceinline__ float bf2f(ushort_t u) {
    return __uint_as_float(((uint_t)u) << 16);
}
__device__ __forceinline__ ushort_t f2bf(float x) {
    uint_t b = __float_as_uint(x);
    b += 0x7FFFu + ((b >> 16) & 1u);            // round-to-nearest-even
    return (ushort_t)(b >> 16);
}

// Workspace (~247 MB):
//   emb0b | emb1b | emb2b (bf16 ND each) | KV (bf16 2*ND, interleaved) | Qb (bf16 ND)
//   Bt (3*4096 bf16) | rsE | rsD | penc | pdec | gcurE/gcurD/bbE/bbD
// Staging stE/stD (16.6 MB) aliases KV (dead until qkv_mfma).

// ---------------- emb0 -> bf16 table ----------------------------------------
__global__ __launch_bounds__(256) void convert_emb0(
    const float* __restrict__ uE, const float* __restrict__ iE,
    ushort_t* __restrict__ emb0b) {
    int i = blockIdx.x * 256 + threadIdx.x;
    if (i >= NTOT * 16) return;
    float4 x = (i < N_USERS * 16) ? reinterpret_cast<const float4*>(uE)[i]
                                  : reinterpret_cast<const float4*>(iE)[i - N_USERS * 16];
    ushort4 o;
    o.x = f2bf(x.x); o.y = f2bf(x.y); o.z = f2bf(x.z); o.w = f2bf(x.w);
    reinterpret_cast<ushort4*>(emb0b)[i] = o;
}

// ---------------- qT/kT/vT -> transposed bf16 Bt[c][k] ----------------------
__global__ void bt_prep(const float* __restrict__ qT, const float* __restrict__ kT,
                        const float* __restrict__ vT, ushort_t* __restrict__ Bt) {
    int t = threadIdx.x;
    for (int idx = t; idx < 4096; idx += 256) {
        int k = idx >> 6, c = idx & 63;
        Bt[c * 64 + k]        = f2bf(qT[idx]);
        Bt[4096 + c * 64 + k] = f2bf(kT[idx]);
        Bt[8192 + c * 64 + k] = f2bf(vT[idx]);
    }
}

// ---------------- bucket cursors init ----------------------------------------
__global__ void init_gcur(int* __restrict__ gE, int* __restrict__ gD) {
    int t = threadIdx.x;
    gE[t] = t * CAPS;
    gD[t] = t * CAPS;
}

// ---------------- Phase A: bucket staging (packed records) -------------------
__global__ __launch_bounds__(256) void bucket_stage(
    const int* __restrict__ enc_rows, const int* __restrict__ enc_cols,
    const float* __restrict__ enc_vals, const int* __restrict__ dec_rows,
    const int* __restrict__ dec_cols, int* __restrict__ gcurE,
    int* __restrict__ gcurD, int2* __restrict__ stE, int* __restrict__ stD) {
    __shared__ int cnt[NPBS];
    __shared__ int base[NPBS];
    __shared__ int run[NPBS];
    int t = threadIdx.x;
    bool enc = blockIdx.x < NCH;
    int cb = (enc ? blockIdx.x : blockIdx.x - NCH) * SCHUNK;
    int ce = min(cb + SCHUNK, NEDGE);
    const int* rows = enc ? enc_rows : dec_rows;
    cnt[t] = 0; run[t] = 0;
    __syncthreads();
    for (int i = cb + t; i < ce; i += 256) atomicAdd(&cnt[rows[i] / BROWS2], 1);
    __syncthreads();
    base[t] = atomicAdd(enc ? &gcurE[t] : &gcurD[t], cnt[t]);
    __syncthreads();
    if (enc) {
        for (int i = cb + t; i < ce; i += 256) {
            int r = rows[i];
            int p = r / BROWS2;
            int off = atomicAdd(&run[p], 1);
            int2 v;
            v.x = ((r - p * BROWS2) << 19) | enc_cols[i];
            v.y = __float_as_int(enc_vals[i]);
            stE[base[p] + off] = v;
        }
    } else {
        for (int i = cb + t; i < ce; i += 256) {
            int r = rows[i];
            int p = r / BROWS2;
            int off = atomicAdd(&run[p], 1);
            stD[base[p] + off] = ((r - p * BROWS2) << 19) | dec_cols[i];
        }
    }
}

// ---------------- bucket-count scan (one block) ------------------------------
__global__ __launch_bounds__(256) void scanB(
    const int* __restrict__ gcurE, const int* __restrict__ gcurD,
    int* __restrict__ bbE, int* __restrict__ bbD,
    int* __restrict__ rsE, int* __restrict__ rsD) {
    __shared__ int sh[256];
    int t = threadIdx.x;
    int c = gcurE[t] - t * CAPS;
    sh[t] = c; __syncthreads();
    for (int off = 1; off < 256; off <<= 1) {
        int x = (t >= off) ? sh[t - off] : 0; __syncthreads();
        sh[t] += x; __syncthreads();
    }
    bbE[t] = sh[t] - c;
    __syncthreads();
    int cd = gcurD[t] - t * CAPS;
    sh[t] = cd; __syncthreads();
    for (int off = 1; off < 256; off <<= 1) {
        int x = (t >= off) ? sh[t - off] : 0; __syncthreads();
        sh[t] += x; __syncthreads();
    }
    bbD[t] = sh[t] - cd;
    if (t == 0) { rsE[NTOT] = NEDGE; rsD[NTOT] = NEDGE; }
}

// ---------------- per-bucket LDS counting sort -------------------------------
__global__ __launch_bounds__(256) void sort_b(
    const int* __restrict__ gcurE, const int* __restrict__ gcurD,
    const int* __restrict__ bbE, const int* __restrict__ bbD,
    const int2* __restrict__ stE, const int* __restrict__ stD,
    int2* __restrict__ penc, int* __restrict__ pdec,
    int* __restrict__ rsE, int* __restrict__ rsD) {
    __shared__ int cnt[PAD5];
    __shared__ int rowst[PAD5];
    __shared__ int tsum[256];
    __shared__ int2 outb[CAPS];
    int t = threadIdx.x;
    bool enc = blockIdx.x < NPBS;
    int b = enc ? blockIdx.x : blockIdx.x - NPBS;
    int rowbase = b * BROWS2;
    int s = b * CAPS;
    int e = enc ? gcurE[b] : gcurD[b];
    int gbase = enc ? bbE[b] : bbD[b];
    int n = e - s;

    for (int i = t; i < PAD5; i += 256) cnt[i] = 0;
    __syncthreads();
    if (enc) {
        for (int i = s + t; i < e; i += 256)
            atomicAdd(&cnt[((uint_t)stE[i].x) >> 19], 1);
    } else {
        for (int i = s + t; i < e; i += 256)
            atomicAdd(&cnt[((uint_t)stD[i]) >> 19], 1);
    }
    __syncthreads();
    int b5 = t * 5, sum = 0;
#pragma unroll
    for (int k = 0; k < 5; ++k) { int c = cnt[b5 + k]; rowst[b5 + k] = sum; sum += c; }
    tsum[t] = sum; __syncthreads();
    for (int off = 1; off < 256; off <<= 1) {
        int x = (t >= off) ? tsum[t - off] : 0; __syncthreads();
        tsum[t] += x; __syncthreads();
    }
    int excl = tsum[t] - sum;
#pragma unroll
    for (int k = 0; k < 5; ++k) {
        rowst[b5 + k] += excl;
        cnt[b5 + k] = rowst[b5 + k];            // cnt becomes the scatter cursor
    }
    __syncthreads();

    if (enc) {
        for (int i = s + t; i < e; i += 256) {
            int2 v = stE[i];
            int lr = ((uint_t)v.x) >> 19;
            int pos = atomicAdd(&cnt[lr], 1);
            outb[pos] = make_int2(v.x & 0x7FFFF, v.y);
        }
        __syncthreads();
        for (int i = t; i < n; i += 256) penc[gbase + i] = outb[i];
        int nrows = min(BROWS2, NTOT - rowbase);
        for (int j = t; j < nrows; j += 256) rsE[rowbase + j] = gbase + rowst[j];
    } else {
        int* ob = (int*)outb;
        for (int i = s + t; i < e; i += 256) {
            int v = stD[i];
            int pos = atomicAdd(&cnt[((uint_t)v) >> 19], 1);
            ob[pos] = v & 0x7FFFF;
        }
        __syncthreads();
        for (int i = t; i < n; i += 256) pdec[gbase + i] = ob[i];
        int nrows = min(BROWS2, NTOT - rowbase);
        for (int j = t; j < nrows; j += 256) rsD[rowbase + j] = gbase + rowst[j];
    }
}

// ---------------- GCN spmm layer (generic): dst = bf16(spmm(src)) ------------
// 32 lanes/row = 2 edge-slots x 16 dim-lanes.
__global__ __launch_bounds__(256) void gcn_gather(
    const int* __restrict__ rsE, const int2* __restrict__ penc,
    const ushort_t* __restrict__ src, ushort_t* __restrict__ dst) {
    int tid = blockIdx.x * 256 + threadIdx.x;
    int row = tid >> 5;
    if (row >= NTOT) return;
    int lane = threadIdx.x & 31;
    int slot = lane >> 4, l = lane & 15;
    int s = rsE[row], e = rsE[row + 1];
    float4 acc = {0.f, 0.f, 0.f, 0.f};
    for (int j = s + slot; j < e; j += 2) {
        int2 cv = penc[j];
        float v = __int_as_float(cv.y);
        ushort4 xb = reinterpret_cast<const ushort4*>(src + (size_t)cv.x * DIM)[l];
        acc.x += v * bf2f(xb.x); acc.y += v * bf2f(xb.y);
        acc.z += v * bf2f(xb.z); acc.w += v * bf2f(xb.w);
    }
    acc.x += __shfl_xor(acc.x, 16); acc.y += __shfl_xor(acc.y, 16);
    acc.z += __shfl_xor(acc.z, 16); acc.w += __shfl_xor(acc.w, 16);
    if (slot == 0) {
        ushort4 o;
        o.x = f2bf(acc.x); o.y = f2bf(acc.y); o.z = f2bf(acc.z); o.w = f2bf(acc.w);
        reinterpret_cast<ushort4*>(dst)[(size_t)row * 16 + l] = o;
    }
}

// ---------------- MFMA Q/K/V; Qb bf16, KV interleaved per 4-elem chunk -------
// KV row layout: chunk i (i=0..15) = [k(4i..4i+3), v(4i..4i+3)]  (16 bf16)
__global__ __launch_bounds__(256) void qkv_mfma(
    const ushort_t* __restrict__ emb2b, const ushort_t* __restrict__ Bt,
    ushort_t* __restrict__ Qb, ushort_t* __restrict__ KV) {
    int tid = threadIdx.x;
    int w = tid >> 6, lane = tid & 63;
    int lr = lane & 15, lh = lane >> 4;
    int R0 = blockIdx.x * 256 + w * 64;

    short8 a[4][2];
    short8 z8 = {0, 0, 0, 0, 0, 0, 0, 0};
#pragma unroll
    for (int m = 0; m < 4; ++m) {
        int row = R0 + m * 16 + lr;
        if (row < NTOT) {
            const ushort_t* ap = emb2b + (size_t)row * 64 + lh * 8;
            a[m][0] = *reinterpret_cast<const short8*>(ap);
            a[m][1] = *reinterpret_cast<const short8*>(ap + 32);
        } else {
            a[m][0] = z8; a[m][1] = z8;
        }
    }

#pragma unroll
    for (int n = 0; n < 4; ++n) {
        int col = n * 16 + lr;
        const ushort_t* bp = Bt + (size_t)col * 64 + lh * 8;
        short8 bq0 = *reinterpret_cast<const short8*>(bp);
        short8 bq1 = *reinterpret_cast<const short8*>(bp + 32);
        short8 bk0 = *reinterpret_cast<const short8*>(bp + 4096);
        short8 bk1 = *reinterpret_cast<const short8*>(bp + 4096 + 32);
        short8 bv0 = *reinterpret_cast<const short8*>(bp + 8192);
        short8 bv1 = *reinterpret_cast<const short8*>(bp + 8192 + 32);
        int ip = ((col >> 2) << 3) + (col & 3);    // interleaved position
#pragma unroll
        for (int m = 0; m < 4; ++m) {
            f32x4 aq = {0.f, 0.f, 0.f, 0.f};
            f32x4 ak = {0.f, 0.f, 0.f, 0.f};
            f32x4 av = {0.f, 0.f, 0.f, 0.f};
            aq = __builtin_amdgcn_mfma_f32_16x16x32_bf16(a[m][0], bq0, aq, 0, 0, 0);
            aq = __builtin_amdgcn_mfma_f32_16x16x32_bf16(a[m][1], bq1, aq, 0, 0, 0);
            ak = __builtin_amdgcn_mfma_f32_16x16x32_bf16(a[m][0], bk0, ak, 0, 0, 0);
            ak = __builtin_amdgcn_mfma_f32_16x16x32_bf16(a[m][1], bk1, ak, 0, 0, 0);
            av = __builtin_amdgcn_mfma_f32_16x16x32_bf16(a[m][0], bv0, av, 0, 0, 0);
            av = __builtin_amdgcn_mfma_f32_16x16x32_bf16(a[m][1], bv1, av, 0, 0, 0);
            int rbase = R0 + m * 16 + lh * 4;
#pragma unroll
            for (int r = 0; r < 4; ++r) {
                int srow = rbase + r;
                if (srow < NTOT) {
                    Qb[(size_t)srow * 64 + col] = f2bf(aq[r]);
                    KV[(size_t)srow * 128 + ip] = f2bf(ak[r]);
                    KV[(size_t)srow * 128 + ip + 4] = f2bf(av[r]);
                }
            }
        }
    }
}

// ---------------- fused GT + layer sum: out = e0+e1+e2 + softmax(QK)V --------
// 32 lanes/row; single out write (no read-modify-write).
__global__ __launch_bounds__(256) void gt_fused(
    const int* __restrict__ rsD, const int* __restrict__ pdec,
    const ushort_t* __restrict__ Qb, const ushort_t* __restrict__ KV,
    const ushort_t* __restrict__ e0b, const ushort_t* __restrict__ e1b,
    const ushort_t* __restrict__ e2b, float* __restrict__ out) {
    int tid = blockIdx.x * 256 + threadIdx.x;
    int row = tid >> 5;
    if (row >= NTOT) return;
    int lane = threadIdx.x & 31;
    int slot = lane >> 4, l = lane & 15;
    int s = rsD[row], e = rsD[row + 1];
    ushort4 qb = reinterpret_cast<const ushort4*>(Qb)[(size_t)row * 16 + l];
    float4 q = {bf2f(qb.x), bf2f(qb.y), bf2f(qb.z), bf2f(qb.w)};
    float norm = 0.f;
    float4 acc = {0.f, 0.f, 0.f, 0.f};
    for (int j = s + slot; j < e; j += 2) {
        int c = pdec[j];
        ushort8 kv = *reinterpret_cast<const ushort8*>(KV + (size_t)c * 128 + l * 8);
        float p = q.x * bf2f(kv[0]) + q.y * bf2f(kv[1])
                + q.z * bf2f(kv[2]) + q.w * bf2f(kv[3]);
        p += __shfl_xor(p, 1);
        p += __shfl_xor(p, 2);
        p = fminf(10.f, fmaxf(-10.f, p));
        float ex = __expf(p);
        norm += ex;
        acc.x += ex * bf2f(kv[4]); acc.y += ex * bf2f(kv[5]);
        acc.z += ex * bf2f(kv[6]); acc.w += ex * bf2f(kv[7]);
    }
    norm  += __shfl_xor(norm, 16);
    acc.x += __shfl_xor(acc.x, 16); acc.y += __shfl_xor(acc.y, 16);
    acc.z += __shfl_xor(acc.z, 16); acc.w += __shfl_xor(acc.w, 16);
    if (slot == 0) {
        float inv = 1.f / (norm + 1e-8f);
        ushort4 a0 = reinterpret_cast<const ushort4*>(e0b)[(size_t)row * 16 + l];
        ushort4 a1 = reinterpret_cast<const ushort4*>(e1b)[(size_t)row * 16 + l];
        ushort4 a2 = reinterpret_cast<const ushort4*>(e2b)[(size_t)row * 16 + l];
        float4 o;
        o.x = bf2f(a0.x) + bf2f(a1.x) + bf2f(a2.x) + acc.x * inv;
        o.y = bf2f(a0.y) + bf2f(a1.y) + bf2f(a2.y) + acc.y * inv;
        o.z = bf2f(a0.z) + bf2f(a1.z) + bf2f(a2.z) + acc.z * inv;
        o.w = bf2f(a0.w) + bf2f(a1.w) + bf2f(a2.w) + acc.w * inv;
        reinterpret_cast<float4*>(out)[(size_t)row * 16 + l] = o;
    }
}

extern "C" void kernel_launch(void* const* d_in, const int* in_sizes, int n_in,
                              void* d_out, int out_size, void* d_ws, size_t ws_size,
                              hipStream_t stream) {
    const float* uE       = (const float*)d_in[0];
    const float* iE       = (const float*)d_in[1];
    const float* qT       = (const float*)d_in[2];
    const float* kT       = (const float*)d_in[3];
    const float* vT       = (const float*)d_in[4];
    const float* enc_vals = (const float*)d_in[5];
    const int*   enc_rows = (const int*)d_in[6];
    const int*   enc_cols = (const int*)d_in[7];
    const int*   dec_rows = (const int*)d_in[8];
    const int*   dec_cols = (const int*)d_in[9];
    float* out = (float*)d_out;

    const size_t ND = (size_t)NTOT * DIM;       // 19.2M
    ushort_t* emb0b = (ushort_t*)d_ws;                      // bf16, ND
    ushort_t* emb1b = emb0b + ND;                           // bf16, ND
    ushort_t* emb2b = emb1b + ND;                           // bf16, ND
    ushort_t* KV    = emb2b + ND;                           // bf16, 2*ND (interleaved)
    ushort_t* Qb    = KV + 2 * ND;                          // bf16, ND
    ushort_t* Bt    = Qb + ND;                              // bf16, 3*4096
    int*      rsE   = (int*)(Bt + 3 * 4096);                // NTOT+1
    int*      rsD   = rsE + NTOT + 1;                       // NTOT+1
    int2*     penc  = (int2*)(rsD + NTOT + 1);              // NEDGE int2
    int*      pdec  = (int*)(penc + NEDGE);                 // NEDGE int
    int*      gcurE = pdec + NEDGE;                         // 256
    int*      gcurD = gcurE + NPBS;                         // 256
    int*      bbE   = gcurD + NPBS;                         // 256
    int*      bbD   = bbE + NPBS;                           // 256

    int2*     stE   = (int2*)KV;                // staging aliases KV (dead until qkv)
    int*      stD   = (int*)(stE + (size_t)NPBS * CAPS);

    const int GB  = (NTOT * 16) / 256;          // 18750
    const int WB2 = (NTOT * 32 + 255) / 256;    // 37500 (2-slot kernels)
    const int QB  = (NTOT + 255) / 256;         // 1172

    init_gcur<<<1, 256, 0, stream>>>(gcurE, gcurD);
    convert_emb0<<<GB, 256, 0, stream>>>(uE, iE, emb0b);
    bt_prep<<<1, 256, 0, stream>>>(qT, kT, vT, Bt);

    bucket_stage<<<2 * NCH, 256, 0, stream>>>(enc_rows, enc_cols, enc_vals,
                                              dec_rows, dec_cols, gcurE, gcurD, stE, stD);
    scanB<<<1, 256, 0, stream>>>(gcurE, gcurD, bbE, bbD, rsE, rsD);
    sort_b<<<2 * NPBS, 256, 0, stream>>>(gcurE, gcurD, bbE, bbD, stE, stD,
                                         penc, pdec, rsE, rsD);

    gcn_gather<<<WB2, 256, 0, stream>>>(rsE, penc, emb0b, emb1b);   // layer 1
    gcn_gather<<<WB2, 256, 0, stream>>>(rsE, penc, emb1b, emb2b);   // layer 2

    qkv_mfma<<<QB, 256, 0, stream>>>(emb2b, Bt, Qb, KV);
    gt_fused<<<WB2, 256, 0, stream>>>(rsD, pdec, Qb, KV, emb0b, emb1b, emb2b, out);
}